// Round 5
// baseline (143.155 us; speedup 1.0000x reference)
//
#include <hip/hip_runtime.h>
#include <hip/hip_bf16.h>

// Block-diagonal matmul: out[t, n*64+e] = sum_d inp[t, n*64+d] * blocks[n, d, e]
// T=16384, 64 blocks of 64x64, fp32 in/out, bf16 MFMA compute.
//
// Round 5: pure concurrency design (latency-bound diagnosis).
//  - BW law from R1-R3: BW ~ 0.075 TB/s * occ% * inflight_bytes -> need ~84.
//  - zero LDS, zero barriers; weights gathered to registers per wave (one-time).
//  - 4096 independent waves: wave wid -> block n = wid/64, strips (wid%64)+64k,
//    k=0..15. Swapped-MFMA fragment recipe validated in round 2.
//  - 3-deep rotating prefetch (12 loads = 192 B/thread in flight, static idx
//    under full unroll), grid = 1024 WGs @ __launch_bounds__(256,4) = exactly
//    4 WGs/CU, single dispatch round, uniform work -> flat ~50% occupancy.

typedef __attribute__((ext_vector_type(8))) short short8;   // 8 bf16
typedef __attribute__((ext_vector_type(4))) float f32x4;

#define D_TOT 4096
#define NK    16                      // strips per wave
#define STEP  ((size_t)64 * 16 * D_TOT)   // 64 strip-slots * 16 rows * 4096

__device__ __forceinline__ short f2b(float x) {
    union { __hip_bfloat16 h; short s; } u;
    u.h = __float2bfloat16(x);
    return u.s;
}

__device__ __forceinline__ short8 cvt8(f32x4 lo, f32x4 hi) {
    short8 a;
    a[0]=f2b(lo[0]); a[1]=f2b(lo[1]); a[2]=f2b(lo[2]); a[3]=f2b(lo[3]);
    a[4]=f2b(hi[0]); a[5]=f2b(hi[1]); a[6]=f2b(hi[2]); a[7]=f2b(hi[3]);
    return a;
}

__global__ __launch_bounds__(256, 4) void block_linear_kernel(
    const float* __restrict__ inp,
    const float* __restrict__ blocks,
    float* __restrict__ out)
{
    const int tid  = threadIdx.x;
    const int wid  = blockIdx.x * 4 + (tid >> 6);   // global wave 0..4095
    const int lane = tid & 63;
    const int g    = lane >> 4;         // k-group
    const int lr   = lane & 15;         // row-within-strip / e-frag index

    const int n  = wid >> 6;            // block index (64 waves per block)
    const int s0 = wid & 63;            // strip slot; strips = s0 + 64k

    // ---- weights -> registers (one-time gather; weights are L2/L3-hot) ----
    // frag (nt,s): lane (g,lr) holds W[d = s*32+8g+i][e = nt*16+lr], i=0..7
    const float* Wn = blocks + (size_t)n * 4096;
    short8 wf[4][2];
    #pragma unroll
    for (int nt = 0; nt < 4; ++nt)
        #pragma unroll
        for (int s = 0; s < 2; ++s) {
            short8 a;
            #pragma unroll
            for (int i = 0; i < 8; ++i)
                a[i] = f2b(Wn[(s * 32 + 8 * g + i) * 64 + nt * 16 + lr]);
            wf[nt][s] = a;
        }

    // this lane's row within a strip: row(k) = (s0 + 64k)*16 + lr
    const float* gin = inp + (size_t)(s0 * 16 + lr) * D_TOT + n * 64 + 8 * g;
    float*      gout = out + (size_t)(s0 * 16 + lr) * D_TOT + n * 64 + g * 4;

    // ---- prologue: fill 3-deep prefetch ----
    f32x4 pf[3][4];
    #pragma unroll
    for (int i = 0; i < 3; ++i) {
        const float* p = gin + (size_t)i * STEP;
        pf[i][0] = *(const f32x4*)(p);
        pf[i][1] = *(const f32x4*)(p + 4);
        pf[i][2] = *(const f32x4*)(p + 32);
        pf[i][3] = *(const f32x4*)(p + 36);
    }

    // ---- main loop: fully unrolled, rotating 3-slot prefetch ----
    #pragma unroll
    for (int k = 0; k < NK; ++k) {
        const int sl = k % 3;           // compile-time under full unroll
        f32x4 a0 = pf[sl][0], a1 = pf[sl][1], a2 = pf[sl][2], a3 = pf[sl][3];
        if (k + 3 < NK) {               // reissue this slot 3 strips ahead
            const float* p = gin + (size_t)(k + 3) * STEP;
            pf[sl][0] = *(const f32x4*)(p);
            pf[sl][1] = *(const f32x4*)(p + 4);
            pf[sl][2] = *(const f32x4*)(p + 32);
            pf[sl][3] = *(const f32x4*)(p + 36);
        }
        short8 b0 = cvt8(a0, a1);       // k-chunk 0..31 of this lane's row
        short8 b1 = cvt8(a2, a3);       // k-chunk 32..63
        float* go = gout + (size_t)k * STEP;
        #pragma unroll
        for (int nt = 0; nt < 4; ++nt) {
            f32x4 acc = (f32x4){0.f, 0.f, 0.f, 0.f};
            acc = __builtin_amdgcn_mfma_f32_16x16x32_bf16(wf[nt][0], b0, acc, 0, 0, 0);
            acc = __builtin_amdgcn_mfma_f32_16x16x32_bf16(wf[nt][1], b1, acc, 0, 0, 0);
            // lane (g,lr) reg j -> out[row][n*64 + nt*16 + g*4 + j]
            *(f32x4*)(go + nt * 16) = acc;
        }
    }
}

extern "C" void kernel_launch(void* const* d_in, const int* in_sizes, int n_in,
                              void* d_out, int out_size, void* d_ws, size_t ws_size,
                              hipStream_t stream) {
    const float* inp    = (const float*)d_in[0];
    const float* blocks = (const float*)d_in[1];
    float* out          = (float*)d_out;

    block_linear_kernel<<<1024, 256, 0, stream>>>(inp, blocks, out);
}

// Round 6
// 142.242 us; speedup vs baseline: 1.0064x; 1.0064x over previous
//
#include <hip/hip_runtime.h>
#include <hip/hip_bf16.h>

// Block-diagonal matmul: out[t, n*64+e] = sum_d inp[t, n*64+d] * blocks[n, d, e]
// T=16384, 64 blocks of 64x64, fp32 in/out, bf16 MFMA compute.
//
// Round 6: R5 structure + PINNED software pipeline.
//  R5 failed because the compiler collapsed the 3-deep prefetch (VGPR=52 vs
//  ~115 needed) and serialized the loads. Fix: template<int K> step() with
//  static slot indices + __builtin_amdgcn_sched_barrier(0) wall per iteration
//  so loads for strip K+3 are pinned ABOVE the wall and compute for strip K
//  below it. Compiler then emits counted vmcnt waits for its own queue.
//  - zero LDS, zero barriers; weights in registers (R2-validated recipe).
//  - 4096 waves: wave wid -> block n = wid/64, strips (wid%64)+64k, k=0..15.
//  - grid 1024 WGs @ __launch_bounds__(256,4): 4 WGs/CU, single round.

typedef __attribute__((ext_vector_type(8))) short short8;   // 8 bf16
typedef __attribute__((ext_vector_type(4))) float f32x4;

#define D_TOT 4096
#define NK    16
#define STEP  ((size_t)64 * 16 * D_TOT)   // 64 strip-slots * 16 rows * 4096

__device__ __forceinline__ short f2b(float x) {
    union { __hip_bfloat16 h; short s; } u;
    u.h = __float2bfloat16(x);
    return u.s;
}

__device__ __forceinline__ short8 cvt8(f32x4 lo, f32x4 hi) {
    short8 a;
    a[0]=f2b(lo[0]); a[1]=f2b(lo[1]); a[2]=f2b(lo[2]); a[3]=f2b(lo[3]);
    a[4]=f2b(hi[0]); a[5]=f2b(hi[1]); a[6]=f2b(hi[2]); a[7]=f2b(hi[3]);
    return a;
}

template<int K>
__device__ __forceinline__ void step(const float* __restrict__ gin,
                                     float* __restrict__ gout,
                                     f32x4 (&pf)[3][4],
                                     const short8 (&wf)[4][2])
{
    constexpr int sl = K % 3;            // static slot (rule #20)

    // consume-copy strip K (compiler inserts counted vmcnt wait here)
    f32x4 a0 = pf[sl][0], a1 = pf[sl][1], a2 = pf[sl][2], a3 = pf[sl][3];

    // reissue this slot for strip K+3 (stays above the wall)
    if constexpr (K + 3 < NK) {
        const float* p = gin + (size_t)(K + 3) * STEP;
        pf[sl][0] = *(const f32x4*)(p);
        pf[sl][1] = *(const f32x4*)(p + 4);
        pf[sl][2] = *(const f32x4*)(p + 32);
        pf[sl][3] = *(const f32x4*)(p + 36);
    }

    __builtin_amdgcn_sched_barrier(0);   // wall: loads above, compute below

    short8 b0 = cvt8(a0, a1);            // k = 0..31 of this lane's row
    short8 b1 = cvt8(a2, a3);            // k = 32..63
    float* go = gout + (size_t)K * STEP;
    #pragma unroll
    for (int nt = 0; nt < 4; ++nt) {
        f32x4 acc = (f32x4){0.f, 0.f, 0.f, 0.f};
        acc = __builtin_amdgcn_mfma_f32_16x16x32_bf16(wf[nt][0], b0, acc, 0, 0, 0);
        acc = __builtin_amdgcn_mfma_f32_16x16x32_bf16(wf[nt][1], b1, acc, 0, 0, 0);
        *(f32x4*)(go + nt * 16) = acc;   // lane (g,lr) reg j -> col nt*16+g*4+j
    }
}

__global__ __launch_bounds__(256, 4) void block_linear_kernel(
    const float* __restrict__ inp,
    const float* __restrict__ blocks,
    float* __restrict__ out)
{
    const int tid  = threadIdx.x;
    const int wid  = blockIdx.x * 4 + (tid >> 6);   // global wave 0..4095
    const int lane = tid & 63;
    const int g    = lane >> 4;         // k-group
    const int lr   = lane & 15;         // row-within-strip / e-frag index

    const int n  = wid >> 6;            // block index (64 waves per block)
    const int s0 = wid & 63;            // strip slot; strips = s0 + 64k

    // ---- weights -> registers (one-time gather; L2/L3-hot) ----
    // frag (nt,s): lane (g,lr) holds W[d = s*32+8g+i][e = nt*16+lr], i=0..7
    const float* Wn = blocks + (size_t)n * 4096;
    short8 wf[4][2];
    #pragma unroll
    for (int nt = 0; nt < 4; ++nt)
        #pragma unroll
        for (int s = 0; s < 2; ++s) {
            short8 a;
            #pragma unroll
            for (int i = 0; i < 8; ++i)
                a[i] = f2b(Wn[(s * 32 + 8 * g + i) * 64 + nt * 16 + lr]);
            wf[nt][s] = a;
        }

    const float* gin = inp + (size_t)(s0 * 16 + lr) * D_TOT + n * 64 + 8 * g;
    float*      gout = out + (size_t)(s0 * 16 + lr) * D_TOT + n * 64 + g * 4;

    // ---- prologue: fill 3-deep prefetch (12 loads in flight) ----
    f32x4 pf[3][4];
    #pragma unroll
    for (int i = 0; i < 3; ++i) {
        const float* p = gin + (size_t)i * STEP;
        pf[i][0] = *(const f32x4*)(p);
        pf[i][1] = *(const f32x4*)(p + 4);
        pf[i][2] = *(const f32x4*)(p + 32);
        pf[i][3] = *(const f32x4*)(p + 36);
    }
    __builtin_amdgcn_sched_barrier(0);

    step< 0>(gin, gout, pf, wf);  step< 1>(gin, gout, pf, wf);
    step< 2>(gin, gout, pf, wf);  step< 3>(gin, gout, pf, wf);
    step< 4>(gin, gout, pf, wf);  step< 5>(gin, gout, pf, wf);
    step< 6>(gin, gout, pf, wf);  step< 7>(gin, gout, pf, wf);
    step< 8>(gin, gout, pf, wf);  step< 9>(gin, gout, pf, wf);
    step<10>(gin, gout, pf, wf);  step<11>(gin, gout, pf, wf);
    step<12>(gin, gout, pf, wf);  step<13>(gin, gout, pf, wf);
    step<14>(gin, gout, pf, wf);  step<15>(gin, gout, pf, wf);
}

extern "C" void kernel_launch(void* const* d_in, const int* in_sizes, int n_in,
                              void* d_out, int out_size, void* d_ws, size_t ws_size,
                              hipStream_t stream) {
    const float* inp    = (const float*)d_in[0];
    const float* blocks = (const float*)d_in[1];
    float* out          = (float*)d_out;

    block_linear_kernel<<<1024, 256, 0, stream>>>(inp, blocks, out);
}